// Round 8
// baseline (4580.582 us; speedup 1.0000x reference)
//
#include <hip/hip_runtime.h>
#include <hip/hip_bf16.h>

#define HH 51

typedef _Float16 half8 __attribute__((ext_vector_type(8)));
typedef float f4 __attribute__((ext_vector_type(4)));

__device__ __forceinline__ float bf2f(unsigned short u) {
    return __uint_as_float(((unsigned)u) << 16);
}
__device__ __forceinline__ float loadf(const void* p, size_t i, bool bf) {
    return bf ? bf2f(((const unsigned short*)p)[i]) : ((const float*)p)[i];
}
__device__ __forceinline__ void storef(void* p, size_t i, float v, bool bf) {
    if (bf) ((__hip_bfloat16*)p)[i] = __float2bfloat16(v);
    else    ((float*)p)[i] = v;
}
__device__ __forceinline__ float sigm(float v) {
    float e = __expf(-fabsf(v));
    float s = 1.0f / (1.0f + e);
    return (v >= 0.0f) ? s : 1.0f - s;
}
__device__ __forceinline__ float tanh_fast(float v) {
    float e = __expf(-2.0f * fabsf(v));
    float t = (1.0f - e) / (1.0f + e);
    return (v >= 0.0f) ? t : -t;
}
__device__ __forceinline__ f4 MF(half8 a, half8 b, f4 c) {
    return __builtin_amdgcn_mfma_f32_16x16x32_f16(a, b, c, 0, 0, 0);
}
// wave64 sum via DPP (verified rounds 5/6), result uniform
__device__ __forceinline__ float wave_sum(float x) {
    float s = x, t;
    t = __builtin_bit_cast(float, __builtin_amdgcn_update_dpp(0, __builtin_bit_cast(int, s), 0x111, 0xf, 0xf, true)); s += t;
    t = __builtin_bit_cast(float, __builtin_amdgcn_update_dpp(0, __builtin_bit_cast(int, s), 0x112, 0xf, 0xf, true)); s += t;
    t = __builtin_bit_cast(float, __builtin_amdgcn_update_dpp(0, __builtin_bit_cast(int, s), 0x114, 0xf, 0xf, true)); s += t;
    t = __builtin_bit_cast(float, __builtin_amdgcn_update_dpp(0, __builtin_bit_cast(int, s), 0x118, 0xf, 0xf, true)); s += t;
    t = __builtin_bit_cast(float, __builtin_amdgcn_update_dpp(0, __builtin_bit_cast(int, s), 0x142, 0xa, 0xf, true)); s += t;
    t = __builtin_bit_cast(float, __builtin_amdgcn_update_dpp(0, __builtin_bit_cast(int, s), 0x143, 0xc, 0xf, true)); s += t;
    return __builtin_bit_cast(float, __builtin_amdgcn_readlane(__builtin_bit_cast(int, s), 63));
}

// LDS (20480 B, single wave per block, NO barriers in hot loop):
//   staging stg[160][64] f16 (20480) UNION runtime:
//   h1b @0: f16 [4][64] = {hi b0, hi b1, lo b0, lo b1}  (512 B)
//   h2b @512: same (512 B)
//   gbuf @1024: f32 [3][160][2]  (3840 B)   0:gh1 1:gh2 2:gi2
//   obufL @4864: f32 [64] output staging (256 B)
__global__ __launch_bounds__(64, 1) void gru_kernel(
    const void* __restrict__ xg,
    const void* __restrict__ wih1, const void* __restrict__ whh1,
    const void* __restrict__ bih1, const void* __restrict__ bhh1,
    const void* __restrict__ wih2, const void* __restrict__ whh2,
    const void* __restrict__ bih2, const void* __restrict__ bhh2,
    const void* __restrict__ wlin, const void* __restrict__ blin_p,
    void* __restrict__ dout, int T, int TF)
{
    __shared__ __align__(16) char L[20480];
    _Float16* stg   = (_Float16*)L;
    _Float16* h1b   = (_Float16*)L;
    _Float16* h2b   = (_Float16*)(L + 512);
    float*    gbuf  = (float*)(L + 1024);
    float*    obufL = (float*)(L + 4864);

    const int lane = threadIdx.x;
    const int n16 = lane & 15, quad = lane >> 4;
    const int m2 = n16 & 1;
    const bool li = lane < HH;
    const int il = li ? lane : HH - 1;
    const int b0 = blockIdx.x * 2;

    // runtime dtype detection (fp32 vs bf16), uniform
    bool isbf;
    {
        const unsigned short* u = (const unsigned short*)whh1;
        int ok = 1;
#pragma unroll
        for (int k = 0; k < 16; ++k) {
            unsigned e = (u[2 * k] >> 7) & 0xFF;
            ok &= (e >= 100 && e <= 125) ? 1 : 0;
        }
        isbf = (ok != 0);
    }

    // ---- stage weights one matrix at a time; snapshot ALL B-frags to VGPRs ----
    half8 W[3][10][2];
#pragma unroll
    for (int mt = 0; mt < 3; ++mt) {
        const void* wm = (mt == 0) ? whh1 : (mt == 1) ? whh2 : wih2;
        for (int e = lane; e < 160 * 64; e += 64) {
            int g = e >> 6, k = e & 63;
            float v = 0.0f;
            if (g < 3 * HH) {
                if (k < HH) v = loadf(wm, (size_t)g * HH + k, isbf);
                else if (k == 52) {   // bias slot (h[52] = 1)
                    if (mt == 0)      v = loadf(bhh1, g, isbf) + ((g < 2 * HH) ? loadf(bih1, g, isbf) : 0.0f);
                    else if (mt == 1) v = loadf(bhh2, g, isbf);
                    else              v = loadf(bih2, g, isbf);
                }
            }
            stg[e] = (_Float16)v;
        }
        __syncthreads();
#pragma unroll
        for (int tl = 0; tl < 10; ++tl)
#pragma unroll
            for (int c = 0; c < 2; ++c)
                W[mt][tl][c] = *(const half8*)(stg + (size_t)(16 * tl + n16) * 64 + c * 32 + quad * 8);
        __syncthreads();
    }

    // ---- runtime LDS init (staging region reused) ----
    for (int e = lane; e < 256; e += 64) ((unsigned*)L)[e] = 0u;   // h1b+h2b zero
    if (lane < 2) {
        h1b[lane * 64 + 52] = (_Float16)1.0f;   // bias slots (hi rows)
        h2b[lane * 64 + 52] = (_Float16)1.0f;
    }

    // elementwise constants
    float wr1 = 0, wz1 = 0, wn1 = 0, bn1 = 0, wl = 0;
    if (li) {
        wr1 = loadf(wih1, il, isbf);          wz1 = loadf(wih1, HH + il, isbf);
        wn1 = loadf(wih1, 2 * HH + il, isbf); bn1 = loadf(bih1, 2 * HH + il, isbf);
        wl  = loadf(wlin, il, isbf);
    }
    const float blv = loadf(blin_p, 0, isbf);

    // x prefetch (32 steps/reload): lane l holds x[b0+(l&1)][t0+(l>>1)]
    float xreg = 0.0f;
    { int src = lane >> 1;
      if (src < T) xreg = loadf(xg, (size_t)(b0 + (lane & 1)) * T + src, isbf); }

    // ---- prologue: gbuf[0] = gh1(0) (h1 = bias slot only) ----
    {
        half8 A[2][2];
#pragma unroll
        for (int r = 0; r < 2; ++r)
#pragma unroll
            for (int c = 0; c < 2; ++c)
                A[r][c] = *(const half8*)(h1b + (r * 2 + m2) * 64 + c * 32 + quad * 8);
#pragma unroll
        for (int tl = 0; tl < 10; ++tl) {
            f4 acc = {0.f, 0.f, 0.f, 0.f};
            acc = MF(A[0][0], W[0][tl][0], acc);
            acc = MF(A[0][1], W[0][tl][1], acc);
            acc = MF(A[1][0], W[0][tl][0], acc);
            acc = MF(A[1][1], W[0][tl][1], acc);
            if (lane < 16) {
                float2 v2; v2.x = acc[0]; v2.y = acc[1];
                *(float2*)&gbuf[(16 * tl + lane) * 2] = v2;
            }
        }
    }

    float h1p0 = 0, h1p1 = 0, h2p0 = 0, h2p1 = 0;
    float out0 = 0, out1 = 0;

    for (int t = 0; t < TF; ++t) {
        const int sl = t & 31;
        float2 g1r = *(float2*)&gbuf[(0 * 160 + il) * 2];
        float2 g1z = *(float2*)&gbuf[(0 * 160 + HH + il) * 2];
        float2 g1n = *(float2*)&gbuf[(0 * 160 + 2 * HH + il) * 2];

        if (t > 0) {   // e2(t-1) + out(t-1)
            float2 hr = *(float2*)&gbuf[(1 * 160 + il) * 2];
            float2 hz = *(float2*)&gbuf[(1 * 160 + HH + il) * 2];
            float2 hn = *(float2*)&gbuf[(1 * 160 + 2 * HH + il) * 2];
            float2 ir = *(float2*)&gbuf[(2 * 160 + il) * 2];
            float2 iz = *(float2*)&gbuf[(2 * 160 + HH + il) * 2];
            float2 nn = *(float2*)&gbuf[(2 * 160 + 2 * HH + il) * 2];
            float p0 = 0.f, p1 = 0.f;
            {
                float r2 = sigm(ir.x + hr.x), z2 = sigm(iz.x + hz.x);
                float n2 = tanh_fast(nn.x + r2 * hn.x);
                float h = n2 + z2 * (h2p0 - n2); h2p0 = h;
                if (li) {
                    _Float16 hi = (_Float16)h;
                    h2b[il] = hi; h2b[128 + il] = (_Float16)(h - (float)hi);
                    p0 = h * wl;
                }
            }
            {
                float r2 = sigm(ir.y + hr.y), z2 = sigm(iz.y + hz.y);
                float n2 = tanh_fast(nn.y + r2 * hn.y);
                float h = n2 + z2 * (h2p1 - n2); h2p1 = h;
                if (li) {
                    _Float16 hi = (_Float16)h;
                    h2b[64 + il] = hi; h2b[192 + il] = (_Float16)(h - (float)hi);
                    p1 = h * wl;
                }
            }
            out0 = wave_sum(p0) + blv;
            out1 = wave_sum(p1) + blv;
            int slp = (t - 1) & 31;
            if (lane == 0) { obufL[2 * slp] = out0; obufL[2 * slp + 1] = out1; }
            if (sl == 0) {   // flush outs [t-32, t-1]; reload x for [t, t+31]
                int idx = (t - 32) + (lane >> 1);
                storef(dout, (size_t)(b0 + (lane & 1)) * TF + idx, obufL[lane], isbf);
                if (t < T) {
                    int src = t + (lane >> 1);
                    xreg = (src < T) ? loadf(xg, (size_t)(b0 + (lane & 1)) * T + src, isbf) : 0.0f;
                }
            }
        }

        float xv0, xv1;
        if (t < T) {
            xv0 = __builtin_bit_cast(float, __builtin_amdgcn_readlane(__builtin_bit_cast(int, xreg), 2 * sl));
            xv1 = __builtin_bit_cast(float, __builtin_amdgcn_readlane(__builtin_bit_cast(int, xreg), 2 * sl + 1));
        } else { xv0 = out0; xv1 = out1; }

        {   // e1(t) batch 0
            float r = sigm(fmaf(xv0, wr1, g1r.x));
            float z = sigm(fmaf(xv0, wz1, g1z.x));
            float n = tanh_fast(fmaf(xv0, wn1, bn1) + r * g1n.x);
            float h = n + z * (h1p0 - n); h1p0 = h;
            if (li) {
                _Float16 hi = (_Float16)h;
                h1b[il] = hi; h1b[128 + il] = (_Float16)(h - (float)hi);
            }
        }
        {   // e1(t) batch 1
            float r = sigm(fmaf(xv1, wr1, g1r.y));
            float z = sigm(fmaf(xv1, wz1, g1z.y));
            float n = tanh_fast(fmaf(xv1, wn1, bn1) + r * g1n.y);
            float h = n + z * (h1p1 - n); h1p1 = h;
            if (li) {
                _Float16 hi = (_Float16)h;
                h1b[64 + il] = hi; h1b[192 + il] = (_Float16)(h - (float)hi);
            }
        }

        // ---- matmuls: gh1(t+1)->gbuf[0], gh2(t)->gbuf[1], gi2(t)->gbuf[2] ----
        half8 A1[2][2], A2[2][2];
#pragma unroll
        for (int r = 0; r < 2; ++r)
#pragma unroll
            for (int c = 0; c < 2; ++c) {
                A1[r][c] = *(const half8*)(h1b + (r * 2 + m2) * 64 + c * 32 + quad * 8);
                A2[r][c] = *(const half8*)(h2b + (r * 2 + m2) * 64 + c * 32 + quad * 8);
            }
#pragma unroll
        for (int mt = 0; mt < 3; ++mt)
#pragma unroll
            for (int tl = 0; tl < 10; ++tl) {
                f4 acc = {0.f, 0.f, 0.f, 0.f};
                if (mt == 1) {
                    acc = MF(A2[0][0], W[1][tl][0], acc);
                    acc = MF(A2[0][1], W[1][tl][1], acc);
                    acc = MF(A2[1][0], W[1][tl][0], acc);
                    acc = MF(A2[1][1], W[1][tl][1], acc);
                } else {
                    acc = MF(A1[0][0], W[mt][tl][0], acc);
                    acc = MF(A1[0][1], W[mt][tl][1], acc);
                    acc = MF(A1[1][0], W[mt][tl][0], acc);
                    acc = MF(A1[1][1], W[mt][tl][1], acc);
                }
                if (lane < 16) {
                    float2 v2; v2.x = acc[0]; v2.y = acc[1];
                    *(float2*)&gbuf[(mt * 160 + 16 * tl + lane) * 2] = v2;
                }
            }
    }

    // ---- epilogue: e2(TF-1), out(TF-1), flush tail ----
    {
        float2 hr = *(float2*)&gbuf[(1 * 160 + il) * 2];
        float2 hz = *(float2*)&gbuf[(1 * 160 + HH + il) * 2];
        float2 hn = *(float2*)&gbuf[(1 * 160 + 2 * HH + il) * 2];
        float2 ir = *(float2*)&gbuf[(2 * 160 + il) * 2];
        float2 iz = *(float2*)&gbuf[(2 * 160 + HH + il) * 2];
        float2 nn = *(float2*)&gbuf[(2 * 160 + 2 * HH + il) * 2];
        float p0 = 0.f, p1 = 0.f;
        {
            float r2 = sigm(ir.x + hr.x), z2 = sigm(iz.x + hz.x);
            float n2 = tanh_fast(nn.x + r2 * hn.x);
            float h = n2 + z2 * (h2p0 - n2);
            if (li) p0 = h * wl;
        }
        {
            float r2 = sigm(ir.y + hr.y), z2 = sigm(iz.y + hz.y);
            float n2 = tanh_fast(nn.y + r2 * hn.y);
            float h = n2 + z2 * (h2p1 - n2);
            if (li) p1 = h * wl;
        }
        out0 = wave_sum(p0) + blv;
        out1 = wave_sum(p1) + blv;
        int slp = (TF - 1) & 31;
        if (lane == 0) { obufL[2 * slp] = out0; obufL[2 * slp + 1] = out1; }
        __syncthreads();
        int base = ((TF - 1) >> 5) << 5;
        int rem = TF - base;
        if ((lane >> 1) < rem)
            storef(dout, (size_t)(b0 + (lane & 1)) * TF + base + (lane >> 1), obufL[lane], isbf);
    }
}

extern "C" void kernel_launch(void* const* d_in, const int* in_sizes, int n_in,
                              void* d_out, int out_size, void* d_ws, size_t ws_size,
                              hipStream_t stream) {
    const int B = 2048;
    const int T = in_sizes[0] / B;   // 1000
    const int TF = out_size / B;     // 2000
    gru_kernel<<<dim3(B / 2), dim3(64), 0, stream>>>(
        d_in[0], d_in[1], d_in[2], d_in[3], d_in[4], d_in[5],
        d_in[6], d_in[7], d_in[8], d_in[9], d_in[10],
        d_out, T, TF);
}

// Round 9
// 2724.407 us; speedup vs baseline: 1.6813x; 1.6813x over previous
//
#include <hip/hip_runtime.h>
#include <hip/hip_bf16.h>

#define HH 51
#define TPB 512     // 8 waves; P1: wave=batch; P2: waves 0-2 = one matrix each
#define BPB 8

typedef _Float16 half8 __attribute__((ext_vector_type(8)));
typedef float f4 __attribute__((ext_vector_type(4)));

__device__ __forceinline__ float bf2f(unsigned short u) {
    return __uint_as_float(((unsigned)u) << 16);
}
__device__ __forceinline__ float loadf(const void* p, size_t i, bool bf) {
    return bf ? bf2f(((const unsigned short*)p)[i]) : ((const float*)p)[i];
}
__device__ __forceinline__ void storef(void* p, size_t i, float v, bool bf) {
    if (bf) ((__hip_bfloat16*)p)[i] = __float2bfloat16(v);
    else    ((float*)p)[i] = v;
}
__device__ __forceinline__ float sigm(float v) {
    float e = __expf(-fabsf(v));
    float s = 1.0f / (1.0f + e);
    return (v >= 0.0f) ? s : 1.0f - s;
}
__device__ __forceinline__ float tanh_fast(float v) {
    float e = __expf(-2.0f * fabsf(v));
    float t = (1.0f - e) / (1.0f + e);
    return (v >= 0.0f) ? t : -t;
}
__device__ __forceinline__ f4 MF(half8 a, half8 b, f4 c) {
    return __builtin_amdgcn_mfma_f32_16x16x32_f16(a, b, c, 0, 0, 0);
}
// wave64 sum via DPP (verified rounds 5/6/8), result uniform across lanes
__device__ __forceinline__ float wave_sum(float x) {
    float s = x, t;
    t = __builtin_bit_cast(float, __builtin_amdgcn_update_dpp(0, __builtin_bit_cast(int, s), 0x111, 0xf, 0xf, true)); s += t;
    t = __builtin_bit_cast(float, __builtin_amdgcn_update_dpp(0, __builtin_bit_cast(int, s), 0x112, 0xf, 0xf, true)); s += t;
    t = __builtin_bit_cast(float, __builtin_amdgcn_update_dpp(0, __builtin_bit_cast(int, s), 0x114, 0xf, 0xf, true)); s += t;
    t = __builtin_bit_cast(float, __builtin_amdgcn_update_dpp(0, __builtin_bit_cast(int, s), 0x118, 0xf, 0xf, true)); s += t;
    t = __builtin_bit_cast(float, __builtin_amdgcn_update_dpp(0, __builtin_bit_cast(int, s), 0x142, 0xa, 0xf, true)); s += t;
    t = __builtin_bit_cast(float, __builtin_amdgcn_update_dpp(0, __builtin_bit_cast(int, s), 0x143, 0xc, 0xf, true)); s += t;
    return __builtin_bit_cast(float, __builtin_amdgcn_readlane(__builtin_bit_cast(int, s), 63));
}

__global__ __launch_bounds__(TPB, 2) void gru_kernel(
    const void* __restrict__ xg,
    const void* __restrict__ wih1, const void* __restrict__ whh1,
    const void* __restrict__ bih1, const void* __restrict__ bhh1,
    const void* __restrict__ wih2, const void* __restrict__ whh2,
    const void* __restrict__ bih2, const void* __restrict__ bhh2,
    const void* __restrict__ wlin, const void* __restrict__ blin_p,
    void* __restrict__ dout, int T, int TF)
{
    // separate __shared__ arrays (no unions) so alias analysis can reorder
    __shared__ __align__(16) _Float16 stg[160 * 64];        // 20480 B
    __shared__ __align__(16) float    gbuf[3 * 160 * 9];    // 17280 B (stride 9: conflict-free)
    __shared__ __align__(16) _Float16 h1hi[16 * 72];        // rows=batch(8)+zero(8), 72-stride
    __shared__ __align__(16) _Float16 h1lo[16 * 72];
    __shared__ __align__(16) _Float16 h2hi[16 * 72];
    __shared__ __align__(16) _Float16 h2lo[16 * 72];
    __shared__ float obufL[8 * 36];                          // out staging, 32-step ring

    const int tid = threadIdx.x, w = tid >> 6, lane = tid & 63;
    const int n16 = lane & 15, quad = lane >> 4;
    const bool li = lane < HH;
    const int il = li ? lane : HH - 1;
    const int bg0 = blockIdx.x * BPB;
    const int myb = bg0 + w;

    // runtime dtype detection (fp32 vs bf16), uniform
    bool isbf;
    {
        const unsigned short* u = (const unsigned short*)whh1;
        int ok = 1;
#pragma unroll
        for (int k = 0; k < 16; ++k) {
            unsigned e = (u[2 * k] >> 7) & 0xFF;
            ok &= (e >= 100 && e <= 125) ? 1 : 0;
        }
        isbf = (ok != 0);
    }

    // ---- stage matrices (f16, bias folded at k=52); wave w<3 snapshots matrix w ----
    half8 W[10][2];
#pragma unroll 1
    for (int mt = 0; mt < 3; ++mt) {
        const void* wm = (mt == 0) ? whh1 : (mt == 1) ? whh2 : wih2;
        for (int e = tid; e < 160 * 64; e += TPB) {
            int g = e >> 6, k = e & 63;
            float v = 0.0f;
            if (g < 3 * HH) {
                if (k < HH) v = loadf(wm, (size_t)g * HH + k, isbf);
                else if (k == 52) {
                    if (mt == 0)      v = loadf(bhh1, g, isbf) + ((g < 2 * HH) ? loadf(bih1, g, isbf) : 0.0f);
                    else if (mt == 1) v = loadf(bhh2, g, isbf);
                    else              v = loadf(bih2, g, isbf);
                }
            }
            stg[e] = (_Float16)v;
        }
        __syncthreads();
        if (w == mt) {
#pragma unroll
            for (int tl = 0; tl < 10; ++tl) {
                W[tl][0] = *(const half8*)(stg + (size_t)(16 * tl + n16) * 64 + quad * 8);
                W[tl][1] = *(const half8*)(stg + (size_t)(16 * tl + n16) * 64 + 32 + quad * 8);
            }
        }
        __syncthreads();
    }

    // ---- init runtime LDS ----
    for (int e = tid; e < 1152; e += TPB) { h1hi[e] = (_Float16)0; h1lo[e] = (_Float16)0;
                                            h2hi[e] = (_Float16)0; h2lo[e] = (_Float16)0; }
    for (int e = tid; e < 4320; e += TPB) gbuf[e] = 0.0f;

    // elementwise constants (lane = hidden unit)
    float wr1 = 0, wz1 = 0, wn1 = 0, bn1 = 0, wl = 0;
    if (li) {
        wr1 = loadf(wih1, il, isbf);          wz1 = loadf(wih1, HH + il, isbf);
        wn1 = loadf(wih1, 2 * HH + il, isbf); bn1 = loadf(bih1, 2 * HH + il, isbf);
        wl  = loadf(wlin, il, isbf);
    }
    const float blv = loadf(blin_p, 0, isbf);

    // x prefetch: lane l holds x[myb][t0 + l], 64 steps per reload
    float xreg = 0.0f;
    if (lane < T) xreg = loadf(xg, (size_t)myb * T + lane, isbf);
    __syncthreads();
    if (tid < BPB) { h1hi[tid * 72 + 52] = (_Float16)1.0f; h2hi[tid * 72 + 52] = (_Float16)1.0f; }
    __syncthreads();

    // ---- prologue: wave0 computes gh1(0) from bias-slot h1 ----
    if (w == 0) {
        half8 Ah0 = *(const half8*)(h1hi + n16 * 72 + quad * 8);
        half8 Ah1 = *(const half8*)(h1hi + n16 * 72 + 32 + quad * 8);
        half8 Al0 = *(const half8*)(h1lo + n16 * 72 + quad * 8);
        half8 Al1 = *(const half8*)(h1lo + n16 * 72 + 32 + quad * 8);
#pragma unroll
        for (int tl = 0; tl < 10; ++tl) {
            f4 acc = {0.f, 0.f, 0.f, 0.f};
            acc = MF(Ah0, W[tl][0], acc); acc = MF(Ah1, W[tl][1], acc);
            acc = MF(Al0, W[tl][0], acc); acc = MF(Al1, W[tl][1], acc);
            if (quad < 2) *(f4*)(gbuf + (16 * tl + n16) * 9 + quad * 4) = acc;
        }
    }
    __syncthreads();

    float h1p = 0.0f, h2p = 0.0f, outv = 0.0f;

    for (int t = 0; t < TF; ++t) {
        // ======== P1: all waves elementwise, batch = w ========
        float g1r = gbuf[il * 9 + w];
        float g1z = gbuf[(HH + il) * 9 + w];
        float g1n = gbuf[(2 * HH + il) * 9 + w];
        float p = 0.0f;
        if (t > 0) {   // e2(t-1)
            float ghr = gbuf[1440 + il * 9 + w], ghz = gbuf[1440 + (HH + il) * 9 + w], ghn = gbuf[1440 + (2 * HH + il) * 9 + w];
            float gir = gbuf[2880 + il * 9 + w], giz = gbuf[2880 + (HH + il) * 9 + w], gin = gbuf[2880 + (2 * HH + il) * 9 + w];
            float r2 = sigm(gir + ghr), z2 = sigm(giz + ghz);
            float n2 = tanh_fast(gin + r2 * ghn);
            float h = n2 + z2 * (h2p - n2); h2p = h;
            if (li) {
                _Float16 hi = (_Float16)h;
                h2hi[w * 72 + il] = hi; h2lo[w * 72 + il] = (_Float16)(h - (float)hi);
                p = h * wl;
            }
        }
        float osum = wave_sum(p) + blv;
        if (t > 0) {
            outv = osum;
            if (lane == 0) obufL[w * 36 + ((t - 1) & 31)] = outv;
        }
        float xv = (t < T) ? __builtin_bit_cast(float, __builtin_amdgcn_readlane(__builtin_bit_cast(int, xreg), t & 63))
                           : outv;
        {   // e1(t)
            float r = sigm(fmaf(xv, wr1, g1r));
            float z = sigm(fmaf(xv, wz1, g1z));
            float n = tanh_fast(fmaf(xv, wn1, bn1) + r * g1n);
            float h = n + z * (h1p - n); h1p = h;
            if (li) {
                _Float16 hi = (_Float16)h;
                h1hi[w * 72 + il] = hi; h1lo[w * 72 + il] = (_Float16)(h - (float)hi);
            }
        }
        __syncthreads();

        // ======== P2: waves 0-2 matmul (one matrix each); waves 3-7 flush ========
        if (w < 3) {
            // wave0: gh1(t+1)=h1@Whh1 ; wave1: gh2(t)=h2@Whh2 ; wave2: gi2(t)=h1@Wih2
            const _Float16* ah = (w == 1) ? h2hi : h1hi;
            const _Float16* al = (w == 1) ? h2lo : h1lo;
            half8 Ah0 = *(const half8*)(ah + n16 * 72 + quad * 8);
            half8 Ah1 = *(const half8*)(ah + n16 * 72 + 32 + quad * 8);
            half8 Al0 = *(const half8*)(al + n16 * 72 + quad * 8);
            half8 Al1 = *(const half8*)(al + n16 * 72 + 32 + quad * 8);
            float* dst = gbuf + w * 1440;
#pragma unroll
            for (int tl = 0; tl < 10; ++tl) {
                f4 acc = {0.f, 0.f, 0.f, 0.f};
                acc = MF(Ah0, W[tl][0], acc); acc = MF(Ah1, W[tl][1], acc);
                acc = MF(Al0, W[tl][0], acc); acc = MF(Al1, W[tl][1], acc);
                if (quad < 2) *(f4*)(dst + (16 * tl + n16) * 9 + quad * 4) = acc;
            }
        } else if ((t & 31) == 0 && t > 0) {
            int et = (w - 3) * 64 + lane;
            if (et < 256) {
                int b = et >> 5, tt = et & 31;
                storef(dout, (size_t)(bg0 + b) * TF + (t - 32) + tt, obufL[b * 36 + tt], isbf);
            }
        }
        if ((t & 63) == 63 && (t + 1) < T) {   // x reload for [t+1, t+64]
            int src = t + 1 + lane;
            xreg = (src < T) ? loadf(xg, (size_t)myb * T + src, isbf) : 0.0f;
        }
        __syncthreads();
    }

    // ---- epilogue: e2(TF-1) + out(TF-1) + tail flush ----
    {
        float ghr = gbuf[1440 + il * 9 + w], ghz = gbuf[1440 + (HH + il) * 9 + w], ghn = gbuf[1440 + (2 * HH + il) * 9 + w];
        float gir = gbuf[2880 + il * 9 + w], giz = gbuf[2880 + (HH + il) * 9 + w], gin = gbuf[2880 + (2 * HH + il) * 9 + w];
        float p = 0.0f;
        float r2 = sigm(gir + ghr), z2 = sigm(giz + ghz);
        float n2 = tanh_fast(gin + r2 * ghn);
        float h = n2 + z2 * (h2p - n2);
        if (li) p = h * wl;
        float osum = wave_sum(p) + blv;
        if (lane == 0) obufL[w * 36 + ((TF - 1) & 31)] = osum;
    }
    __syncthreads();
    {
        int base = (TF - 1) & ~31, rem = TF - base;
        if (tid < 256) {
            int b = tid >> 5, tt = tid & 31;
            if (tt < rem)
                storef(dout, (size_t)(bg0 + b) * TF + base + tt, obufL[b * 36 + tt], isbf);
        }
    }
}

extern "C" void kernel_launch(void* const* d_in, const int* in_sizes, int n_in,
                              void* d_out, int out_size, void* d_ws, size_t ws_size,
                              hipStream_t stream) {
    const int B = 2048;
    const int T = in_sizes[0] / B;   // 1000
    const int TF = out_size / B;     // 2000
    gru_kernel<<<dim3(B / BPB), dim3(TPB), 0, stream>>>(
        d_in[0], d_in[1], d_in[2], d_in[3], d_in[4], d_in[5],
        d_in[6], d_in[7], d_in[8], d_in[9], d_in[10],
        d_out, T, TF);
}